// Round 12
// baseline (12534.859 us; speedup 1.0000x reference)
//
#include <hip/hip_runtime.h>
#include <stdint.h>
#include <stddef.h>

// ===================== problem constants =====================
#define LT    2048
#define BATCH 64
#define NH    256
#define HS_ELEMS  (BATCH * LT * NH)   // 33554432
#define OUT_ELEMS (BATCH * LT * 2)    // 262144
// d_out layout: [hs (B,L,256) | outs (B,L,2) | priors (B,L,16)] fp32
// d_ws layout:  [r-dump 32MB | W_res bf16 frags 128KB | W_sf bf16 frags 128KB]
#define WS_DUMP_BYTES   ((size_t)BATCH * LT * NH * 2)     // 32 MiB
#define WS_STREAM_BYTES (2 * 131072)

typedef __attribute__((ext_vector_type(8))) __bf16 bf16x8;
typedef __attribute__((ext_vector_type(4))) float  f32x4;
typedef __attribute__((ext_vector_type(2))) unsigned u32x2;
typedef __attribute__((ext_vector_type(8))) unsigned short u16x8;

// v_cvt_pk_bf16_f32: dst = {lo16: bf16(a), hi16: bf16(b)}, RNE
static __device__ __forceinline__ unsigned pk2(float a, float b) {
  unsigned r;
  asm("v_cvt_pk_bf16_f32 %0, %1, %2" : "=v"(r) : "v"(a), "v"(b));
  return r;
}
static __device__ __forceinline__ bf16x8 pack8v(f32x4 a, f32x4 b) {
  union { unsigned u[4]; bf16x8 v; } r;
  r.u[0] = pk2(a[0], a[1]); r.u[1] = pk2(a[2], a[3]);
  r.u[2] = pk2(b[0], b[1]); r.u[3] = pk2(b[2], b[3]);
  return r.v;
}
static __device__ __forceinline__ bf16x8 pack8(const float* p) {
  return pack8v(*(const f32x4*)p, *(const f32x4*)(p + 4));
}
static __device__ __forceinline__ float bf2f(unsigned short u) {
  unsigned v = ((unsigned)u) << 16;
  return __builtin_bit_cast(float, v);
}

// Raw workgroup barrier: LDS ordered via lgkmcnt(0); vmcnt deliberately NOT
// drained (global prefetch/stream loads and stores stay in flight).
#define BARRIER() do {                                           \
    asm volatile("s_waitcnt lgkmcnt(0)" ::: "memory");           \
    __builtin_amdgcn_s_barrier();                                \
    __builtin_amdgcn_sched_barrier(0);                           \
  } while (0)

// LDS layout (bytes): fragment order, conflict-free b128 ops, single A_s
// buffer + 2 barriers/step (r5/r10-proven; dbuf retired by r11).
#define W_RES_OFF 0        // frag [kk8][n][kg]: off = kk8*16384 + n*64 + kg*16 (128 KiB)
#define A_S_OFF   131072   // frag [kk][lane]: kk*1024 + lane*16; kk<8 h, kk>=8 r (16 KiB)
#define BIASR_OFF 147456   // 64 x f32x4: (b_fs+b_res)
#define LDS_BYTES 148480

// ===================== kernel 0: weight frag pre-conversion ================
// Writes W_res and W_sf as bf16 fragments (chunk c -> byte c*16) into ws.
// c = mat*8192 + kk8*1024 + n*4 + kg ; src k = kk8*32 + kg*8.
__global__ __launch_bounds__(256) void wconvert_kernel(
    const float* __restrict__ W_res, const float* __restrict__ W_sf,
    __bf16* __restrict__ dst)
{
  const int c = blockIdx.x * 256 + threadIdx.x;   // grid 64 -> 16384 chunks
  const int mat = c >> 13, cc = c & 8191;
  const int kk8 = cc >> 10, n = (cc >> 2) & 255, kgs = cc & 3;
  const float* src = (mat ? W_sf : W_res) + (size_t)n * NH + kk8 * 32 + kgs * 8;
  *(bf16x8*)(dst + (size_t)c * 8) = pack8(src);
}

// ===================== kernel 1: u = x @ W_in^T + (b_in+b_hh+b_sf) ==========
__global__ __launch_bounds__(256) void u_precompute_kernel(
    const float* __restrict__ x,      // [B, L, 16]
    const float* __restrict__ W_in,   // [256, 16]
    const float* __restrict__ b_in,
    const float* __restrict__ b_hh,
    const float* __restrict__ b_sf,
    float* __restrict__ u)            // [B, L, 256] (= hs region)
{
  __shared__ float xs[64][16];
  const int tid = threadIdx.x;
  const int b  = blockIdx.x >> 5;
  const int tc = (blockIdx.x & 31) << 6;   // 64 timesteps per block
  float w[16];
#pragma unroll
  for (int i = 0; i < 16; ++i) w[i] = W_in[tid * 16 + i];
  const float bias = b_in[tid] + b_hh[tid] + b_sf[tid];
  for (int r = tid; r < 64 * 16; r += 256)
    xs[r >> 4][r & 15] = x[((size_t)b * LT + tc + (r >> 4)) * 16 + (r & 15)];
  __syncthreads();
  for (int tt = 0; tt < 64; ++tt) {
    float s = bias;
#pragma unroll
    for (int i = 0; i < 16; ++i) s += xs[tt][i] * w[i];
    u[((size_t)b * LT + tc + tt) * NH + tid] = s;
  }
}

// ===================== kernel 2 (mode 0): serial recurrence + VMEM stream ==
// r10 structure (8 waves, 2 tiles/wave, 2 lgkm-only barriers, frag-order LDS,
// coalesced r-dump, priors offloaded) with tile-1 of W_res AND W_sf streamed
// from L2 (ws bf16 frags) via depth-4 pipelines: LDS reads 256->192/CU/step,
// VMEM pipe (idle before) carries 128KB/step in parallel.
// vmcnt ordering: pfU/nzc (HBM/L3, slow) issued at kk==12 — AFTER every
// stream load whose consume follows — so no counted wait on a stream load
// ever forces their retirement; they are 2-generation ping-pong'd via a
// manually 2-step-unrolled t-loop (no copy stall).
__global__ __launch_bounds__(512, 1) void rnn_seq_stream_kernel(
    const float* __restrict__ hidden,     // [B,256]
    const float* __restrict__ reservoir,  // [B,256]
    const float* __restrict__ noise,      // [L,B,256]
    const float* __restrict__ W_hh, const float* __restrict__ W_sf,
    const float* __restrict__ W_fs, const float* __restrict__ W_res,
    const float* __restrict__ b_fs, const float* __restrict__ b_res,
    float* __restrict__ hs,               // [B,L,256] (holds u on entry)
    u32x2* __restrict__ rws8,             // [4][L][1024] frag-order r dump
    const char* __restrict__ wstream)     // bf16 frags: W_res@0, W_sf@128K
{
  extern __shared__ char lds[];
  const int tid  = threadIdx.x;
  const int lane = tid & 63;
  const int wv   = tid >> 6;        // wave 0..7
  const int col  = lane & 15;       // batch row within WG
  const int kg   = lane >> 4;       // k-group 0..3
  const int b0   = blockIdx.x * 16;

  // ---- stage W_res tile0 chunks into LDS frag layout (n bit4 == 0) ----
#pragma unroll 4
  for (int j = 0; j < 16; ++j) {
    const int c   = j * 512 + tid;
    const int kk8 = c >> 10, n = (c >> 2) & 255, kgs = c & 3;
    if ((n & 16) == 0)
      *(bf16x8*)(lds + W_RES_OFF + c * 16) =
          pack8(W_res + (size_t)n * NH + kk8 * 32 + kgs * 8);
  }
  // ---- stage initial state h0 (c=tid) and r0 (c=tid+512) ----
  {
    const int kk = tid >> 6, l16 = tid & 63;
    const int kgs = l16 >> 4, m = l16 & 15;
    *(bf16x8*)(lds + A_S_OFF + tid * 16) =
        pack8(hidden + (size_t)(b0 + m) * NH + kk * 32 + kgs * 8);
    *(bf16x8*)(lds + A_S_OFF + (tid + 512) * 16) =
        pack8(reservoir + (size_t)(b0 + m) * NH + kk * 32 + kgs * 8);
  }
  // ---- stage biases (b_fs+b_res) as 64 f32x4 ----
  if (tid < 64) {
    f32x4 v = *(const f32x4*)(b_fs + tid * 4);
    f32x4 w = *(const f32x4*)(b_res + tid * 4);
    *(f32x4*)(lds + BIASR_OFF + tid * 16) = v + w;
  }

  // ---- resident weight fragments: wHH both tiles, wFS both, wSF tile0 ----
  bf16x8 wHH[2][8], wFS[2][8], wSF0[8];
#pragma unroll
  for (int tile = 0; tile < 2; ++tile) {
    const int n = wv * 32 + tile * 16 + col;
#pragma unroll
    for (int kk = 0; kk < 8; ++kk) {
      wHH[tile][kk] = pack8(W_hh + (size_t)n * NH + kk * 32 + kg * 8);
      wFS[tile][kk] = pack8(W_fs + (size_t)n * NH + kk * 32 + kg * 8);
    }
  }
  {
    const int n = wv * 32 + col;      // tile 0
#pragma unroll
    for (int kk = 0; kk < 8; ++kk)
      wSF0[kk] = pack8(W_sf + (size_t)n * NH + kk * 32 + kg * 8);
  }

  // ---- per-lane stream base: tile1 n = wv*32+16+col ----
  const char* gR = wstream + wv * 2048 + 1024 + col * 64 + kg * 16;
  const char* gS = gR + 131072;

  // ---- state / accumulators / 2-generation prefetch ----
  const size_t hsRow = (size_t)(b0 + col) * (LT * NH);
  const size_t nzRow = (size_t)(b0 + col) * NH;
  f32x4 r_old[2], accH[2], accR[2];
  f32x4 nzA[2], pfA[2], nzB[2], pfB[2];
#pragma unroll
  for (int tile = 0; tile < 2; ++tile) {
    const int nb = wv * 32 + tile * 16 + kg * 4;
    r_old[tile] = *(const f32x4*)(reservoir + nzRow + nb);
    accH[tile]  = *(const f32x4*)(hs + hsRow + nb);                 // u(0)
    nzA[tile]   = *(const f32x4*)(noise + nzRow + nb);              // noise(0)
    pfA[tile]   = *(const f32x4*)(hs + hsRow + NH + nb);            // u(1)
  }

  BARRIER();   // staging visible to all waves

#pragma unroll
  for (int tile = 0; tile < 2; ++tile) {
    const int nb = wv * 32 + tile * 16 + kg * 4;
    accR[tile] = *(const f32x4*)(lds + BIASR_OFF + nb * 4);
  }

  const char* afp = lds + A_S_OFF + lane * 16;
  const char* bwp = lds + W_RES_OFF + (wv * 32) * 64 + col * 64 + kg * 16;

  // One step; NZC/PFU = this step's noise(t)/u(t+1); NZN/PFN = next gen.
#define STEP(T, NZC, PFU, NZN, PFN)                                          \
  {                                                                          \
    bf16x8 sR[4], sS[4];                                                     \
    _Pragma("unroll")                                                        \
    for (int kk = 0; kk < 16; ++kk) {                                        \
      if (kk == 12) {  /* deep prefetch: after all earlier stream issues */  \
        const size_t tq1 = ((T) + 1 < LT) ? (size_t)((T) + 1) : (LT - 1);    \
        const size_t tq2 = ((T) + 2 < LT) ? (size_t)((T) + 2) : (LT - 1);    \
        _Pragma("unroll")                                                    \
        for (int tile = 0; tile < 2; ++tile) {                               \
          const int nb = wv * 32 + tile * 16 + kg * 4;                       \
          NZN[tile] = *(const f32x4*)(noise + tq1 * (BATCH * NH) + nzRow + nb); \
          PFN[tile] = *(const f32x4*)(hs + hsRow + tq2 * NH + nb);           \
        }                                                                    \
      }                                                                      \
      const bf16x8 af = *(const bf16x8*)(afp + kk * 1024);                   \
      if (kk >= 4 && kk < 8) {                                               \
        sR[kk - 4] = *(const bf16x8*)(gR + (kk - 4) * 16384);                \
        sS[kk - 4] = *(const bf16x8*)(gS + (kk - 4) * 16384);                \
      }                                                                      \
      if (kk < 8) {                                                          \
        accH[0] = __builtin_amdgcn_mfma_f32_16x16x32_bf16(wHH[0][kk], af, accH[0], 0, 0, 0); \
        accH[1] = __builtin_amdgcn_mfma_f32_16x16x32_bf16(wHH[1][kk], af, accH[1], 0, 0, 0); \
        accR[0] = __builtin_amdgcn_mfma_f32_16x16x32_bf16(wFS[0][kk], af, accR[0], 0, 0, 0); \
        accR[1] = __builtin_amdgcn_mfma_f32_16x16x32_bf16(wFS[1][kk], af, accR[1], 0, 0, 0); \
      } else {                                                               \
        const int j = kk - 8;                                                \
        accH[0] = __builtin_amdgcn_mfma_f32_16x16x32_bf16(wSF0[j], af, accH[0], 0, 0, 0); \
        accH[1] = __builtin_amdgcn_mfma_f32_16x16x32_bf16(sS[j & 3], af, accH[1], 0, 0, 0); \
        const bf16x8 bw = *(const bf16x8*)(bwp + j * 16384);                 \
        accR[0] = __builtin_amdgcn_mfma_f32_16x16x32_bf16(bw, af, accR[0], 0, 0, 0); \
        accR[1] = __builtin_amdgcn_mfma_f32_16x16x32_bf16(sR[j & 3], af, accR[1], 0, 0, 0); \
        if (kk < 12) {                                                       \
          sR[j] = *(const bf16x8*)(gR + (j + 4) * 16384);                    \
          sS[j] = *(const bf16x8*)(gS + (j + 4) * 16384);                    \
        }                                                                    \
      }                                                                      \
    }                                                                        \
    BARRIER();   /* all reads of A_s done before overwrite */                \
    float* hsT = hs + hsRow + (size_t)(T) * NH;                              \
    char* abase = lds + A_S_OFF + wv * 1024 + col * 16 + (kg & 1) * 8;       \
    _Pragma("unroll")                                                        \
    for (int tile = 0; tile < 2; ++tile) {                                   \
      const int nb = wv * 32 + tile * 16 + kg * 4;                           \
      f32x4 hv, rv;                                                          \
      _Pragma("unroll")                                                      \
      for (int j = 0; j < 4; ++j) {                                          \
        hv[j] = fmaxf(accH[tile][j], 0.f) + NZC[tile][j];   /* af = 1 */     \
        rv[j] = 0.9f * r_old[tile][j] + 0.1f * fmaxf(accR[tile][j], 0.f);    \
      }                                                                      \
      r_old[tile] = rv;                                                      \
      *(f32x4*)(hsT + nb) = hv;                                              \
      u32x2 hp, rp;                                                          \
      hp[0] = pk2(hv[0], hv[1]); hp[1] = pk2(hv[2], hv[3]);                  \
      rp[0] = pk2(rv[0], rv[1]); rp[1] = pk2(rv[2], rv[3]);                  \
      char* dst = abase + (2 * tile + (kg >> 1)) * 256;                      \
      *(u32x2*)dst          = hp;                                            \
      *(u32x2*)(dst + 8192) = rp;                                            \
      rws8[((size_t)blockIdx.x * LT + (T)) * 1024 + tile * 512 + tid] = rp;  \
    }                                                                        \
    _Pragma("unroll")                                                        \
    for (int tile = 0; tile < 2; ++tile) {                                   \
      const int nb = wv * 32 + tile * 16 + kg * 4;                           \
      accH[tile] = PFU[tile];                              /* u(T+1) */      \
      accR[tile] = *(const f32x4*)(lds + BIASR_OFF + nb * 4);                \
    }                                                                        \
    BARRIER();   /* A_s restaged for next step */                            \
  }

#pragma unroll 1
  for (int t = 0; t < LT; t += 2) {
    STEP(t,     nzA, pfA, nzB, pfB)
    STEP(t + 1, nzB, pfB, nzA, pfA)
  }
#undef STEP
}

// ===================== kernel 2 (mode 1, fallback): r10 all-LDS version ====
__global__ __launch_bounds__(512, 1) void rnn_seq_fallback_kernel(
    const float* __restrict__ hidden, const float* __restrict__ reservoir,
    const float* __restrict__ noise,
    const float* __restrict__ W_hh, const float* __restrict__ W_sf,
    const float* __restrict__ W_fs, const float* __restrict__ W_res,
    const float* __restrict__ b_fs, const float* __restrict__ b_res,
    const float* __restrict__ W_pr, const float* __restrict__ b_pr,
    float* __restrict__ hs, float* __restrict__ priors)
{
  extern __shared__ char lds[];
  const int tid  = threadIdx.x;
  const int lane = tid & 63;
  const int wv   = tid >> 6;
  const int col  = lane & 15;
  const int kg   = lane >> 4;
  const int b0   = blockIdx.x * 16;

#pragma unroll 4
  for (int j = 0; j < 16; ++j) {
    const int c   = j * 512 + tid;
    const int kk8 = c >> 10, n = (c >> 2) & 255, kgs = c & 3;
    *(bf16x8*)(lds + W_RES_OFF + c * 16) =
        pack8(W_res + (size_t)n * NH + kk8 * 32 + kgs * 8);
  }
  {
    const int kk = tid >> 6, l16 = tid & 63;
    const int kgs = l16 >> 4, m = l16 & 15;
    *(bf16x8*)(lds + A_S_OFF + tid * 16) =
        pack8(hidden + (size_t)(b0 + m) * NH + kk * 32 + kgs * 8);
    *(bf16x8*)(lds + A_S_OFF + (tid + 512) * 16) =
        pack8(reservoir + (size_t)(b0 + m) * NH + kk * 32 + kgs * 8);
  }
  if (tid < 64) {
    f32x4 v = *(const f32x4*)(b_fs + tid * 4);
    f32x4 w = *(const f32x4*)(b_res + tid * 4);
    *(f32x4*)(lds + BIASR_OFF + tid * 16) = v + w;
  }

  bf16x8 wHH[2][8], wSF[2][8], wFS[2][8], wPR[8];
#pragma unroll
  for (int tile = 0; tile < 2; ++tile) {
    const int n = wv * 32 + tile * 16 + col;
#pragma unroll
    for (int kk = 0; kk < 8; ++kk) {
      wHH[tile][kk] = pack8(W_hh + (size_t)n * NH + kk * 32 + kg * 8);
      wSF[tile][kk] = pack8(W_sf + (size_t)n * NH + kk * 32 + kg * 8);
      wFS[tile][kk] = pack8(W_fs + (size_t)n * NH + kk * 32 + kg * 8);
    }
  }
#pragma unroll
  for (int kk8 = 0; kk8 < 8; ++kk8)
    wPR[kk8] = pack8(W_pr + (size_t)col * NH + kk8 * 32 + kg * 8);
  const f32x4 bp4 = *(const f32x4*)(b_pr + kg * 4);

  const size_t hsRow = (size_t)(b0 + col) * (LT * NH);
  const size_t nzRow = (size_t)(b0 + col) * NH;
  f32x4 r_old[2], accH[2], accR[2], accP;
#pragma unroll
  for (int tile = 0; tile < 2; ++tile) {
    const int nb = wv * 32 + tile * 16 + kg * 4;
    r_old[tile] = *(const f32x4*)(reservoir + nzRow + nb);
    accH[tile]  = *(const f32x4*)(hs + hsRow + nb);
  }
  accP = bp4;
  BARRIER();
#pragma unroll
  for (int tile = 0; tile < 2; ++tile) {
    const int nb = wv * 32 + tile * 16 + kg * 4;
    accR[tile] = *(const f32x4*)(lds + BIASR_OFF + nb * 4);
  }

#pragma unroll 1
  for (int t = 0; t < LT; ++t) {
    const size_t tp1 = (t + 1 < LT) ? (size_t)(t + 1) : (size_t)(LT - 1);
    f32x4 pfU[2], nzc[2];
#pragma unroll
    for (int tile = 0; tile < 2; ++tile) {
      const int nb = wv * 32 + tile * 16 + kg * 4;
      pfU[tile] = *(const f32x4*)(hs + hsRow + tp1 * NH + nb);
      nzc[tile] = *(const f32x4*)(noise + (size_t)t * (BATCH * NH) + nzRow + nb);
    }
    const char* afp = lds + A_S_OFF + lane * 16;
    const char* bwp = lds + W_RES_OFF + (wv * 32) * 64 + col * 64 + kg * 16;
#pragma unroll
    for (int kk = 0; kk < 16; ++kk) {
      const bf16x8 af = *(const bf16x8*)(afp + kk * 1024);
      if (kk < 8) {
#pragma unroll
        for (int tile = 0; tile < 2; ++tile)
          accH[tile] = __builtin_amdgcn_mfma_f32_16x16x32_bf16(wHH[tile][kk], af, accH[tile], 0, 0, 0);
#pragma unroll
        for (int tile = 0; tile < 2; ++tile)
          accR[tile] = __builtin_amdgcn_mfma_f32_16x16x32_bf16(wFS[tile][kk], af, accR[tile], 0, 0, 0);
      } else {
#pragma unroll
        for (int tile = 0; tile < 2; ++tile)
          accH[tile] = __builtin_amdgcn_mfma_f32_16x16x32_bf16(wSF[tile][kk - 8], af, accH[tile], 0, 0, 0);
#pragma unroll
        for (int tile = 0; tile < 2; ++tile) {
          const bf16x8 bw = *(const bf16x8*)(bwp + (kk - 8) * 16384 + tile * 1024);
          accR[tile] = __builtin_amdgcn_mfma_f32_16x16x32_bf16(bw, af, accR[tile], 0, 0, 0);
        }
        if (wv == 1)
          accP = __builtin_amdgcn_mfma_f32_16x16x32_bf16(wPR[kk - 8], af, accP, 0, 0, 0);
      }
    }
    BARRIER();
    float* hsT = hs + hsRow + (size_t)t * NH;
    char* abase = lds + A_S_OFF + wv * 1024 + col * 16 + (kg & 1) * 8;
#pragma unroll
    for (int tile = 0; tile < 2; ++tile) {
      const int nb = wv * 32 + tile * 16 + kg * 4;
      f32x4 hv, rv;
#pragma unroll
      for (int j = 0; j < 4; ++j) {
        hv[j] = fmaxf(accH[tile][j], 0.f) + nzc[tile][j];
        rv[j] = 0.9f * r_old[tile][j] + 0.1f * fmaxf(accR[tile][j], 0.f);
      }
      r_old[tile] = rv;
      *(f32x4*)(hsT + nb) = hv;
      u32x2 hp, rp;
      hp[0] = pk2(hv[0], hv[1]); hp[1] = pk2(hv[2], hv[3]);
      rp[0] = pk2(rv[0], rv[1]); rp[1] = pk2(rv[2], rv[3]);
      char* dst = abase + (2 * tile + (kg >> 1)) * 256;
      *(u32x2*)dst          = hp;
      *(u32x2*)(dst + 8192) = rp;
    }
    if (wv == 1 && t > 0) {
      f32x4 pv;
#pragma unroll
      for (int j = 0; j < 4; ++j) pv[j] = 1.f / (1.f + __expf(-accP[j]));
      *(f32x4*)(priors + (size_t)(b0 + col) * (LT * 16) + (size_t)(t - 1) * 16 + kg * 4) = pv;
    }
#pragma unroll
    for (int tile = 0; tile < 2; ++tile) {
      const int nb = wv * 32 + tile * 16 + kg * 4;
      accH[tile] = pfU[tile];
      accR[tile] = *(const f32x4*)(lds + BIASR_OFF + nb * 4);
    }
    accP = bp4;
    BARRIER();
  }
  if (wv == 1) {
    f32x4 aP = bp4;
    const char* afp2 = lds + A_S_OFF + 8192 + lane * 16;
#pragma unroll
    for (int kk8 = 0; kk8 < 8; ++kk8) {
      const bf16x8 af = *(const bf16x8*)(afp2 + kk8 * 1024);
      aP = __builtin_amdgcn_mfma_f32_16x16x32_bf16(wPR[kk8], af, aP, 0, 0, 0);
    }
    f32x4 pv;
#pragma unroll
    for (int j = 0; j < 4; ++j) pv[j] = 1.f / (1.f + __expf(-aP[j]));
    *(f32x4*)(priors + (size_t)(b0 + col) * (LT * 16) + (size_t)(LT - 1) * 16 + kg * 4) = pv;
  }
}

// ===================== kernel 3: priors from frag-order dump (mode 0) ======
__global__ __launch_bounds__(256) void prior_post_kernel(
    const u32x2* __restrict__ rws8,
    const float* __restrict__ W_pr,          // [16,256]
    const float* __restrict__ b_pr,          // [16]
    float* __restrict__ priors)              // [B,L,16]
{
  __shared__ unsigned short rs[8 * 16 * 256];   // 64 KiB: 8 steps x 16 batch
  const int tid = threadIdx.x;
  const int wg = blockIdx.x >> 8;               // grid = 4*256
  const int t0 = (blockIdx.x & 255) * 8;
#pragma unroll 4
  for (int i = 0; i < 32; ++i) {
    const int ci = i * 256 + tid;               // [0, 8192)
    const int tt = ci >> 10, c = ci & 1023;
    const u32x2 v = rws8[((size_t)wg * LT + t0 + tt) * 1024 + c];
    const int tile = c >> 9, t2 = c & 511;
    const int wvv = t2 >> 6, kgg = (t2 >> 4) & 3, cl = t2 & 15;
    const int n0 = wvv * 32 + tile * 16 + kgg * 4;
    *(u32x2*)(rs + ((tt * 16 + cl) << 8) + n0) = v;
  }
  __syncthreads();
  const int n = tid & 15, g = tid >> 4;
  const float* wrow = W_pr + n * NH;
  const float bp = b_pr[n];
  for (int pp = 0; pp < 8; ++pp) {
    const int p = g * 8 + pp;
    const int tt = p >> 4, cl = p & 15;
    const unsigned short* rr = rs + ((tt * 16 + cl) << 8);
    float s = bp;
#pragma unroll 8
    for (int k8 = 0; k8 < 32; ++k8) {
      const f32x4 w0 = *(const f32x4*)(wrow + k8 * 8);
      const f32x4 w1 = *(const f32x4*)(wrow + k8 * 8 + 4);
      const u16x8 a = *(const u16x8*)(rr + k8 * 8);
#pragma unroll
      for (int j = 0; j < 4; ++j)
        s += bf2f(a[j]) * w0[j] + bf2f(a[j + 4]) * w1[j];
    }
    priors[((size_t)(wg * 16 + cl) * LT + t0 + tt) * 16 + n] =
        1.f / (1.f + __expf(-s));
  }
}

// ===================== kernel 4: out = clip(hs @ W_out^T + b_out) ==========
__global__ __launch_bounds__(256) void out_project_kernel(
    const float* __restrict__ hs,     // [B*L, 256]
    const float* __restrict__ W_out,  // [2, 256]
    const float* __restrict__ b_out,  // [2]
    float* __restrict__ outs)         // [B*L, 2]
{
  const int tid = threadIdx.x;
  const int lane = tid & 63;
  const int wv = tid >> 6;
  const int row0 = blockIdx.x * 64 + wv * 16;
  f32x4 w0 = *(const f32x4*)(W_out + lane * 4);
  f32x4 w1 = *(const f32x4*)(W_out + 256 + lane * 4);
  const float bo0 = b_out[0], bo1 = b_out[1];
  for (int i = 0; i < 16; ++i) {
    const f32x4 h = *(const f32x4*)(hs + (size_t)(row0 + i) * NH + lane * 4);
    float p0 = h[0]*w0[0] + h[1]*w0[1] + h[2]*w0[2] + h[3]*w0[3];
    float p1 = h[0]*w1[0] + h[1]*w1[1] + h[2]*w1[2] + h[3]*w1[3];
#pragma unroll
    for (int off = 32; off; off >>= 1) {
      p0 += __shfl_down(p0, off, 64);
      p1 += __shfl_down(p1, off, 64);
    }
    if (lane == 0) {
      const size_t o = (size_t)(row0 + i) * 2;
      outs[o]     = fminf(fmaxf(p0 + bo0, -2.f), 2.f);
      outs[o + 1] = fminf(fmaxf(p1 + bo1, -2.f), 2.f);
    }
  }
}

// ===================== launch =====================
extern "C" void kernel_launch(void* const* d_in, const int* in_sizes, int n_in,
                              void* d_out, int out_size, void* d_ws, size_t ws_size,
                              hipStream_t stream) {
  const float* x         = (const float*)d_in[0];
  const float* hidden    = (const float*)d_in[1];
  const float* reservoir = (const float*)d_in[2];
  const float* noise     = (const float*)d_in[3];
  const float* W_in      = (const float*)d_in[4];
  const float* b_in      = (const float*)d_in[5];
  const float* W_hh      = (const float*)d_in[6];
  const float* b_hh      = (const float*)d_in[7];
  const float* W_sf      = (const float*)d_in[8];
  const float* b_sf      = (const float*)d_in[9];
  const float* W_fs      = (const float*)d_in[10];
  const float* b_fs      = (const float*)d_in[11];
  const float* W_res     = (const float*)d_in[12];
  const float* b_res     = (const float*)d_in[13];
  const float* W_out     = (const float*)d_in[14];
  const float* b_out     = (const float*)d_in[15];
  const float* W_pr      = (const float*)d_in[16];
  const float* b_pr      = (const float*)d_in[17];

  float* hs     = (float*)d_out;
  float* outs   = hs + HS_ELEMS;
  float* priors = outs + OUT_ELEMS;
  u32x2* rws8   = (u32x2*)d_ws;
  char*  wstream = (char*)d_ws + WS_DUMP_BYTES;

  u_precompute_kernel<<<2048, 256, 0, stream>>>(x, W_in, b_in, b_hh, b_sf, hs);

  if (ws_size >= WS_DUMP_BYTES + WS_STREAM_BYTES) {
    wconvert_kernel<<<64, 256, 0, stream>>>(W_res, W_sf, (__bf16*)wstream);
    hipFuncSetAttribute((const void*)rnn_seq_stream_kernel,
                        hipFuncAttributeMaxDynamicSharedMemorySize, LDS_BYTES);
    rnn_seq_stream_kernel<<<4, 512, LDS_BYTES, stream>>>(
        hidden, reservoir, noise, W_hh, W_sf, W_fs, W_res,
        b_fs, b_res, hs, rws8, wstream);
    prior_post_kernel<<<1024, 256, 0, stream>>>(rws8, W_pr, b_pr, priors);
  } else {
    hipFuncSetAttribute((const void*)rnn_seq_fallback_kernel,
                        hipFuncAttributeMaxDynamicSharedMemorySize, LDS_BYTES);
    rnn_seq_fallback_kernel<<<4, 512, LDS_BYTES, stream>>>(
        hidden, reservoir, noise, W_hh, W_sf, W_fs, W_res,
        b_fs, b_res, W_pr, b_pr, hs, priors);
  }

  out_project_kernel<<<2048, 256, 0, stream>>>(hs, W_out, b_out, outs);
}

// Round 13
// 5594.615 us; speedup vs baseline: 2.2405x; 2.2405x over previous
//
#include <hip/hip_runtime.h>
#include <stdint.h>
#include <stddef.h>

// ===================== problem constants =====================
#define LT    2048
#define BATCH 64
#define NH    256
#define HS_ELEMS  (BATCH * LT * NH)   // 33554432
#define OUT_ELEMS (BATCH * LT * 2)    // 262144
// d_out layout: [hs (B,L,256) | outs (B,L,2) | priors (B,L,16)] fp32

typedef __attribute__((ext_vector_type(8))) __bf16 bf16x8;
typedef __attribute__((ext_vector_type(4))) float  f32x4;
typedef __attribute__((ext_vector_type(2))) unsigned u32x2;
typedef __attribute__((ext_vector_type(8))) unsigned short u16x8;

// v_cvt_pk_bf16_f32: dst = {lo16: bf16(a), hi16: bf16(b)}, RNE
static __device__ __forceinline__ unsigned pk2(float a, float b) {
  unsigned r;
  asm("v_cvt_pk_bf16_f32 %0, %1, %2" : "=v"(r) : "v"(a), "v"(b));
  return r;
}
static __device__ __forceinline__ bf16x8 pack8v(f32x4 a, f32x4 b) {
  union { unsigned u[4]; bf16x8 v; } r;
  r.u[0] = pk2(a[0], a[1]); r.u[1] = pk2(a[2], a[3]);
  r.u[2] = pk2(b[0], b[1]); r.u[3] = pk2(b[2], b[3]);
  return r.v;
}
static __device__ __forceinline__ bf16x8 pack8(const float* p) {
  return pack8v(*(const f32x4*)p, *(const f32x4*)(p + 4));
}
static __device__ __forceinline__ float bf2f(unsigned short u) {
  unsigned v = ((unsigned)u) << 16;
  return __builtin_bit_cast(float, v);
}

// Raw workgroup barrier: LDS ordered via lgkmcnt(0); vmcnt deliberately NOT
// drained (global prefetch loads / stores stay in flight across the barrier).
#define BARRIER() do {                                           \
    asm volatile("s_waitcnt lgkmcnt(0)" ::: "memory");           \
    __builtin_amdgcn_s_barrier();                                \
    asm volatile("" ::: "memory");                               \
  } while (0)

// LDS layout (bytes): ALL hot data in MFMA-fragment order -> every wave-wide
// LDS op touches consecutive 16B chunks (conflict-free) and uses one address
// register + immediate offsets. Single A_s buffer + 2 barriers/step.
// RETIRED by A/B: double-buffer (r11 -16%), 4-wave (r9 -67%), VMEM weight
// streaming (r12 -130%), in-loop x-fold (r4), launch-bounds cap (r6/r7).
#define W_RES_OFF 0        // frag [kk8][n][kg]: off = kk8*16384 + n*64 + kg*16 (128 KiB)
#define A_S_OFF   131072   // frag [kk][lane]: kk*1024 + lane*16; kk<8 h, kk>=8 r (16 KiB)
#define BIASR_OFF 147456   // 64 x f32x4: (b_fs+b_res)
#define LDS_BYTES 148480

// ===================== kernel 1: u = x @ W_in^T + (b_in+b_hh+b_sf) ==========
__global__ __launch_bounds__(256) void u_precompute_kernel(
    const float* __restrict__ x,      // [B, L, 16]
    const float* __restrict__ W_in,   // [256, 16]
    const float* __restrict__ b_in,
    const float* __restrict__ b_hh,
    const float* __restrict__ b_sf,
    float* __restrict__ u)            // [B, L, 256] (= hs region)
{
  __shared__ float xs[64][16];
  const int tid = threadIdx.x;
  const int b  = blockIdx.x >> 5;
  const int tc = (blockIdx.x & 31) << 6;   // 64 timesteps per block
  float w[16];
#pragma unroll
  for (int i = 0; i < 16; ++i) w[i] = W_in[tid * 16 + i];
  const float bias = b_in[tid] + b_hh[tid] + b_sf[tid];
  for (int r = tid; r < 64 * 16; r += 256)
    xs[r >> 4][r & 15] = x[((size_t)b * LT + tc + (r >> 4)) * 16 + (r & 15)];
  __syncthreads();
  for (int tt = 0; tt < 64; ++tt) {
    float s = bias;
#pragma unroll
    for (int i = 0; i < 16; ++i) s += xs[tt][i] * w[i];
    u[((size_t)b * LT + tc + tt) * NH + tid] = s;
  }
}

// ===================== kernel 2: the serial recurrence =====================
// r10 champion structure: 8 waves x 64 lanes, wave owns 32 out cols (2 tiles)
// for tmp_h and tmp_r; weights = MFMA A-operand (VGPRs), state = B-operand
// (LDS bf16, fragment order, single buffer, 2 lgkm-only barriers/step);
// u(t+1)/noise(t) prefetched into regs at K-loop start.
// PRIOR_MODE 0 (default): NO prior work in-loop — all 8 waves identical (no
//   straggler skew at barriers). Epilogue dumps r(t) bf16 with coalesced
//   8B/lane stores; post-kernel computes priors.
// PRIOR_MODE 1 (ws-too-small fallback): wave-1 in-loop prior (wPR in regs).
template<int PRIOR_MODE>
__global__ __launch_bounds__(512, 1) void rnn_seq_kernel(
    const float* __restrict__ hidden,     // [B,256]
    const float* __restrict__ reservoir,  // [B,256]
    const float* __restrict__ noise,      // [L,B,256]
    const float* __restrict__ W_hh, const float* __restrict__ W_sf,
    const float* __restrict__ W_fs, const float* __restrict__ W_res,
    const float* __restrict__ b_fs, const float* __restrict__ b_res,
    const float* __restrict__ W_pr, const float* __restrict__ b_pr,
    float* __restrict__ hs,               // [B,L,256] (holds u on entry)
    float* __restrict__ priors,           // [B,L,16]
    u32x2* __restrict__ rws8)             // [4][L][1024] frag-order r dump
{
  extern __shared__ char lds[];
  const int tid  = threadIdx.x;
  const int lane = tid & 63;
  const int wv   = tid >> 6;        // wave 0..7
  const int col  = lane & 15;       // batch row within WG
  const int kg   = lane >> 4;       // k-group 0..3
  const int b0   = blockIdx.x * 16;

  // ---- stage W_res into frag layout: chunk c -> addr c*16 (coalesced) ----
  // c = kk8*1024 + n*4 + kg ; src k = kk8*32 + kg*8
#pragma unroll 4
  for (int j = 0; j < 16; ++j) {
    const int c   = j * 512 + tid;
    const int kk8 = c >> 10, n = (c >> 2) & 255, kgs = c & 3;
    *(bf16x8*)(lds + W_RES_OFF + c * 16) =
        pack8(W_res + (size_t)n * NH + kk8 * 32 + kgs * 8);
  }
  // ---- stage initial state h0 (c=tid) and r0 (c=tid+512) ----
  {
    const int kk = tid >> 6, l16 = tid & 63;
    const int kgs = l16 >> 4, m = l16 & 15;
    *(bf16x8*)(lds + A_S_OFF + tid * 16) =
        pack8(hidden + (size_t)(b0 + m) * NH + kk * 32 + kgs * 8);
    *(bf16x8*)(lds + A_S_OFF + (tid + 512) * 16) =
        pack8(reservoir + (size_t)(b0 + m) * NH + kk * 32 + kgs * 8);
  }
  // ---- stage biases (b_fs+b_res) as 64 f32x4 ----
  if (tid < 64) {
    f32x4 v = *(const f32x4*)(b_fs + tid * 4);
    f32x4 w = *(const f32x4*)(b_res + tid * 4);
    *(f32x4*)(lds + BIASR_OFF + tid * 16) = v + w;
  }

  // ---- per-lane weight fragments (A-operand), 2 tiles per wave ----
  bf16x8 wHH[2][8], wSF[2][8], wFS[2][8];
#pragma unroll
  for (int tile = 0; tile < 2; ++tile) {
    const int n = wv * 32 + tile * 16 + col;
#pragma unroll
    for (int kk = 0; kk < 8; ++kk) {
      wHH[tile][kk] = pack8(W_hh + (size_t)n * NH + kk * 32 + kg * 8);
      wSF[tile][kk] = pack8(W_sf + (size_t)n * NH + kk * 32 + kg * 8);
      wFS[tile][kk] = pack8(W_fs + (size_t)n * NH + kk * 32 + kg * 8);
    }
  }
  // mode-1 only: prior weights/bias in registers (fallback path)
  bf16x8 wPR[PRIOR_MODE ? 8 : 1];
  f32x4 bp4;
  if (PRIOR_MODE) {
#pragma unroll
    for (int kk8 = 0; kk8 < 8; ++kk8)
      wPR[kk8] = pack8(W_pr + (size_t)col * NH + kk8 * 32 + kg * 8);
    bp4 = *(const f32x4*)(b_pr + kg * 4);
  }

  // ---- state / accH init (globals: no LDS dependence, safe pre-barrier) --
  const size_t hsRow = (size_t)(b0 + col) * (LT * NH);
  const size_t nzRow = (size_t)(b0 + col) * NH;
  f32x4 r_old[2], accH[2], accR[2], accP;
#pragma unroll
  for (int tile = 0; tile < 2; ++tile) {
    const int nb = wv * 32 + tile * 16 + kg * 4;
    r_old[tile] = *(const f32x4*)(reservoir + nzRow + nb);
    accH[tile]  = *(const f32x4*)(hs + hsRow + nb);                 // u(0)
  }
  if (PRIOR_MODE) accP = bp4;

  BARRIER();   // staging visible to all waves

  // accR init AFTER barrier (reads wave-0-written LDS biases)
#pragma unroll
  for (int tile = 0; tile < 2; ++tile) {
    const int nb = wv * 32 + tile * 16 + kg * 4;
    accR[tile] = *(const f32x4*)(lds + BIASR_OFF + nb * 4);
  }

#pragma unroll 1
  for (int t = 0; t < LT; ++t) {
    // ---- issue global prefetch: u(t+1) and noise(t); consumed in epilogue --
    const size_t tp1 = (t + 1 < LT) ? (size_t)(t + 1) : (size_t)(LT - 1);
    f32x4 pfU[2], nzc[2];
#pragma unroll
    for (int tile = 0; tile < 2; ++tile) {
      const int nb = wv * 32 + tile * 16 + kg * 4;
      pfU[tile] = *(const f32x4*)(hs + hsRow + tp1 * NH + nb);
      nzc[tile] = *(const f32x4*)(noise + (size_t)t * (BATCH * NH) + nzRow + nb);
    }

    // -------- K-loop: K=512 over [h | r], 16 k-steps --------
    const char* afp = lds + A_S_OFF + lane * 16;          // + kk*1024 imm
    const char* bwp = lds + W_RES_OFF + (wv * 32) * 64 + col * 64 + kg * 16;
#pragma unroll
    for (int kk = 0; kk < 16; ++kk) {
      const bf16x8 af = *(const bf16x8*)(afp + kk * 1024);
      if (kk < 8) {
#pragma unroll
        for (int tile = 0; tile < 2; ++tile)
          accH[tile] = __builtin_amdgcn_mfma_f32_16x16x32_bf16(wHH[tile][kk], af, accH[tile], 0, 0, 0);
#pragma unroll
        for (int tile = 0; tile < 2; ++tile)
          accR[tile] = __builtin_amdgcn_mfma_f32_16x16x32_bf16(wFS[tile][kk], af, accR[tile], 0, 0, 0);
      } else {
#pragma unroll
        for (int tile = 0; tile < 2; ++tile)
          accH[tile] = __builtin_amdgcn_mfma_f32_16x16x32_bf16(wSF[tile][kk - 8], af, accH[tile], 0, 0, 0);
#pragma unroll
        for (int tile = 0; tile < 2; ++tile) {
          const bf16x8 bw = *(const bf16x8*)(bwp + (kk - 8) * 16384 + tile * 1024);
          accR[tile] = __builtin_amdgcn_mfma_f32_16x16x32_bf16(bw, af, accR[tile], 0, 0, 0);
        }
        if (PRIOR_MODE && wv == 1) {
          accP = __builtin_amdgcn_mfma_f32_16x16x32_bf16(wPR[kk - 8], af, accP, 0, 0, 0);
        }
      }
    }
    BARRIER();   // all reads of A_s done before overwrite (no vmcnt drain)

    // -------- epilogue: update state, store h, dump r, restage A_s ---------
    // h element n -> chunk kk=wv, sub-chunk kg'=2*tile+(kg>>1), byte 8*(kg&1)
    float* hsT = hs + hsRow + (size_t)t * NH;
    char* abase = lds + A_S_OFF + wv * 1024 + col * 16 + (kg & 1) * 8;
#pragma unroll
    for (int tile = 0; tile < 2; ++tile) {
      const int nb = wv * 32 + tile * 16 + kg * 4;
      f32x4 hv, rv;
#pragma unroll
      for (int j = 0; j < 4; ++j) {
        hv[j] = fmaxf(accH[tile][j], 0.f) + nzc[tile][j];     // alpha_fast = 1
        rv[j] = 0.9f * r_old[tile][j] + 0.1f * fmaxf(accR[tile][j], 0.f);
      }
      r_old[tile] = rv;
      *(f32x4*)(hsT + nb) = hv;                 // fire-and-forget store
      u32x2 hp, rp;
      hp[0] = pk2(hv[0], hv[1]); hp[1] = pk2(hv[2], hv[3]);
      rp[0] = pk2(rv[0], rv[1]); rp[1] = pk2(rv[2], rv[3]);
      char* dst = abase + (2 * tile + (kg >> 1)) * 256;
      *(u32x2*)dst          = hp;
      *(u32x2*)(dst + 8192) = rp;               // r chunks at kk+8
      if (!PRIOR_MODE)                          // coalesced frag-order dump
        rws8[((size_t)blockIdx.x * LT + t) * 1024 + tile * 512 + tid] = rp;
    }
    if (PRIOR_MODE && wv == 1 && t > 0) {
      f32x4 pv;
#pragma unroll
      for (int j = 0; j < 4; ++j) pv[j] = 1.f / (1.f + __expf(-accP[j]));
      *(f32x4*)(priors + (size_t)(b0 + col) * (LT * 16) + (size_t)(t - 1) * 16 + kg * 4) = pv;
    }

    // -------- reinit accumulators for next step --------
#pragma unroll
    for (int tile = 0; tile < 2; ++tile) {
      const int nb = wv * 32 + tile * 16 + kg * 4;
      accH[tile] = pfU[tile];                                   // u(t+1)
      accR[tile] = *(const f32x4*)(lds + BIASR_OFF + nb * 4);
    }
    if (PRIOR_MODE) accP = bp4;
    BARRIER();   // A_s restaged for next step (no vmcnt drain)
  }

  // -------- tail (mode 1): prior_{L-1} from staged r_{L-1} --------
  if (PRIOR_MODE && wv == 1) {
    f32x4 aP = bp4;
    const char* afp2 = lds + A_S_OFF + 8192 + lane * 16;   // r chunks
#pragma unroll
    for (int kk8 = 0; kk8 < 8; ++kk8) {
      const bf16x8 af = *(const bf16x8*)(afp2 + kk8 * 1024);
      aP = __builtin_amdgcn_mfma_f32_16x16x32_bf16(wPR[kk8], af, aP, 0, 0, 0);
    }
    f32x4 pv;
#pragma unroll
    for (int j = 0; j < 4; ++j) pv[j] = 1.f / (1.f + __expf(-aP[j]));
    *(f32x4*)(priors + (size_t)(b0 + col) * (LT * 16) + (size_t)(LT - 1) * 16 + kg * 4) = pv;
  }
}

// ===================== kernel 3: priors from frag-order dump (mode 0) ======
// rws8 chunk c at (wg,t): tile=c>>9, tid=c&511 -> wv=tid>>6, kg=(tid>>4)&3,
// col=tid&15; chunk = r[b=wg*16+col][t][n0..n0+3], n0 = wv*32+tile*16+kg*4.
__global__ __launch_bounds__(256) void prior_post_kernel(
    const u32x2* __restrict__ rws8,
    const float* __restrict__ W_pr,          // [16,256]
    const float* __restrict__ b_pr,          // [16]
    float* __restrict__ priors)              // [B,L,16]
{
  __shared__ unsigned short rs[8 * 16 * 256];   // 64 KiB: 8 steps x 16 batch
  const int tid = threadIdx.x;
  const int wg = blockIdx.x >> 8;               // grid = 4*256
  const int t0 = (blockIdx.x & 255) * 8;
#pragma unroll 4
  for (int i = 0; i < 32; ++i) {
    const int ci = i * 256 + tid;               // [0, 8192)
    const int tt = ci >> 10, c = ci & 1023;
    const u32x2 v = rws8[((size_t)wg * LT + t0 + tt) * 1024 + c];
    const int tile = c >> 9, t2 = c & 511;
    const int wvv = t2 >> 6, kgg = (t2 >> 4) & 3, cl = t2 & 15;
    const int n0 = wvv * 32 + tile * 16 + kgg * 4;
    *(u32x2*)(rs + ((tt * 16 + cl) << 8) + n0) = v;
  }
  __syncthreads();
  const int n = tid & 15, g = tid >> 4;
  const float* wrow = W_pr + n * NH;            // L2-hot across blocks
  const float bp = b_pr[n];
  for (int pp = 0; pp < 8; ++pp) {
    const int p = g * 8 + pp;                   // [0,128): 8t x 16b pairs
    const int tt = p >> 4, cl = p & 15;
    const unsigned short* rr = rs + ((tt * 16 + cl) << 8);
    float s = bp;
#pragma unroll 8
    for (int k8 = 0; k8 < 32; ++k8) {
      const f32x4 w0 = *(const f32x4*)(wrow + k8 * 8);
      const f32x4 w1 = *(const f32x4*)(wrow + k8 * 8 + 4);
      const u16x8 a = *(const u16x8*)(rr + k8 * 8);
#pragma unroll
      for (int j = 0; j < 4; ++j)
        s += bf2f(a[j]) * w0[j] + bf2f(a[j + 4]) * w1[j];
    }
    priors[((size_t)(wg * 16 + cl) * LT + t0 + tt) * 16 + n] =
        1.f / (1.f + __expf(-s));
  }
}

// ===================== kernel 4: out = clip(hs @ W_out^T + b_out) ==========
__global__ __launch_bounds__(256) void out_project_kernel(
    const float* __restrict__ hs,     // [B*L, 256]
    const float* __restrict__ W_out,  // [2, 256]
    const float* __restrict__ b_out,  // [2]
    float* __restrict__ outs)         // [B*L, 2]
{
  const int tid = threadIdx.x;
  const int lane = tid & 63;
  const int wv = tid >> 6;
  const int row0 = blockIdx.x * 64 + wv * 16;   // 16 rows per wave
  f32x4 w0 = *(const f32x4*)(W_out + lane * 4);
  f32x4 w1 = *(const f32x4*)(W_out + 256 + lane * 4);
  const float bo0 = b_out[0], bo1 = b_out[1];
  for (int i = 0; i < 16; ++i) {
    const f32x4 h = *(const f32x4*)(hs + (size_t)(row0 + i) * NH + lane * 4);
    float p0 = h[0]*w0[0] + h[1]*w0[1] + h[2]*w0[2] + h[3]*w0[3];
    float p1 = h[0]*w1[0] + h[1]*w1[1] + h[2]*w1[2] + h[3]*w1[3];
#pragma unroll
    for (int off = 32; off; off >>= 1) {
      p0 += __shfl_down(p0, off, 64);
      p1 += __shfl_down(p1, off, 64);
    }
    if (lane == 0) {
      const size_t o = (size_t)(row0 + i) * 2;
      outs[o]     = fminf(fmaxf(p0 + bo0, -2.f), 2.f);
      outs[o + 1] = fminf(fmaxf(p1 + bo1, -2.f), 2.f);
    }
  }
}

// ===================== launch =====================
extern "C" void kernel_launch(void* const* d_in, const int* in_sizes, int n_in,
                              void* d_out, int out_size, void* d_ws, size_t ws_size,
                              hipStream_t stream) {
  const float* x         = (const float*)d_in[0];
  const float* hidden    = (const float*)d_in[1];
  const float* reservoir = (const float*)d_in[2];
  const float* noise     = (const float*)d_in[3];
  const float* W_in      = (const float*)d_in[4];
  const float* b_in      = (const float*)d_in[5];
  const float* W_hh      = (const float*)d_in[6];
  const float* b_hh      = (const float*)d_in[7];
  const float* W_sf      = (const float*)d_in[8];
  const float* b_sf      = (const float*)d_in[9];
  const float* W_fs      = (const float*)d_in[10];
  const float* b_fs      = (const float*)d_in[11];
  const float* W_res     = (const float*)d_in[12];
  const float* b_res     = (const float*)d_in[13];
  const float* W_out     = (const float*)d_in[14];
  const float* b_out     = (const float*)d_in[15];
  const float* W_pr      = (const float*)d_in[16];
  const float* b_pr      = (const float*)d_in[17];

  float* hs     = (float*)d_out;
  float* outs   = hs + HS_ELEMS;
  float* priors = outs + OUT_ELEMS;
  u32x2* rws8   = (u32x2*)d_ws;

  const size_t rws_bytes = (size_t)BATCH * LT * NH * sizeof(unsigned short);

  u_precompute_kernel<<<2048, 256, 0, stream>>>(x, W_in, b_in, b_hh, b_sf, hs);

  if (ws_size >= rws_bytes) {
    hipFuncSetAttribute((const void*)&rnn_seq_kernel<0>,
                        hipFuncAttributeMaxDynamicSharedMemorySize, LDS_BYTES);
    rnn_seq_kernel<0><<<4, 512, LDS_BYTES, stream>>>(
        hidden, reservoir, noise, W_hh, W_sf, W_fs, W_res,
        b_fs, b_res, W_pr, b_pr, hs, priors, rws8);
    prior_post_kernel<<<1024, 256, 0, stream>>>(rws8, W_pr, b_pr, priors);
  } else {
    hipFuncSetAttribute((const void*)&rnn_seq_kernel<1>,
                        hipFuncAttributeMaxDynamicSharedMemorySize, LDS_BYTES);
    rnn_seq_kernel<1><<<4, 512, LDS_BYTES, stream>>>(
        hidden, reservoir, noise, W_hh, W_sf, W_fs, W_res,
        b_fs, b_res, W_pr, b_pr, hs, priors, rws8);
  }

  out_project_kernel<<<2048, 256, 0, stream>>>(hs, W_out, b_out, outs);
}